// Round 14
// baseline (327.238 us; speedup 1.0000x reference)
//
#include <hip/hip_runtime.h>

#define N_NODES 50000
#define N_EDGES 800000
#define F_INPUT 256
#define HDIM 64
#define NCLS 10
#define NGRAPH 64

#define BSHIFT 7                 // 128 nodes per bucket
#define NBUCK 391                // ceil(50000/128)
#define SCAP 4096                // per-bucket stage/eadj capacity (mean 2046, 45 sigma)

// ---------------- pass A: LDS-staged bucket partition ----------------
__global__ __launch_bounds__(256) void k_part(const int* __restrict__ src,
                                              const int* __restrict__ dst,
                                              int* __restrict__ bcnt,
                                              int* __restrict__ stage, int E) {
    __shared__ int cnt[NBUCK];
    __shared__ int base[NBUCK];
    const int tid = threadIdx.x;
    const int e0 = blockIdx.x * 4096;
    int pb[16], pv[16];
    for (int t = tid; t < NBUCK; t += 256) cnt[t] = 0;
    __syncthreads();
#pragma unroll
    for (int j = 0; j < 16; ++j) {
        int e = e0 + j * 256 + tid;
        if (e < E) {
            int s = src[e], d = dst[e];
            pb[j] = d >> BSHIFT;
            pv[j] = (s << BSHIFT) | (d & 127);
            atomicAdd(&cnt[pb[j]], 1);
        } else pb[j] = -1;
    }
    __syncthreads();
    for (int t = tid; t < NBUCK; t += 256) {
        int c = cnt[t];
        base[t] = c ? atomicAdd(&bcnt[t], c) : 0;
        cnt[t] = 0;
    }
    __syncthreads();
#pragma unroll
    for (int j = 0; j < 16; ++j) {
        if (pb[j] >= 0) {
            int r = base[pb[j]] + atomicAdd(&cnt[pb[j]], 1);
            if (r < SCAP) stage[pb[j] * SCAP + r] = pv[j];  // 45-sigma clamp
        }
    }
}

// ---------------- pass B: per-bucket degree + scan + counting sort ----------------
__global__ __launch_bounds__(256) void k_csr(const int* __restrict__ stage,
                                             const int* __restrict__ bcnt,
                                             int* __restrict__ degi,
                                             float* __restrict__ dis,
                                             int* __restrict__ off,
                                             int* __restrict__ eadj, int n) {
    __shared__ int cnt[128];
    __shared__ int loc[128];
    __shared__ int lcur[128];
    __shared__ int ebuf[SCAP];   // 16 KB
    const int b = blockIdx.x;
    const int tid = threadIdx.x;
    const int n0 = b << BSHIFT;
    const int nn = min(128, n - n0);
    const int sb = b * SCAP;
    const int len = min(bcnt[b], SCAP);
    if (tid < 128) cnt[tid] = 0;
    __syncthreads();
    for (int j = tid; j < len; j += 256) atomicAdd(&cnt[stage[sb + j] & 127], 1);
    __syncthreads();
    if (tid < nn) {
        int dg = cnt[tid];
        degi[n0 + tid] = dg;
        dis[n0 + tid] = rsqrtf((float)(dg + 1));
    }
    if (tid < 128) loc[tid] = cnt[tid];
    __syncthreads();
    for (int d = 1; d < 128; d <<= 1) {       // Hillis-Steele inclusive scan
        int x = 0;
        if (tid < 128 && tid >= d) x = loc[tid - d];
        __syncthreads();
        if (tid < 128) loc[tid] += x;
        __syncthreads();
    }
    if (tid < 128) {
        int ex = loc[tid] - cnt[tid];          // exclusive
        if (tid < nn) off[n0 + tid] = sb + ex;
        lcur[tid] = ex;
    }
    __syncthreads();
    for (int j = tid; j < len; j += 256) {
        int p = stage[sb + j];
        int rk = atomicAdd(&lcur[p & 127], 1);
        ebuf[rk] = p >> BSHIFT;
    }
    __syncthreads();
    for (int j = tid; j < len; j += 256) eadj[sb + j] = ebuf[j];  // linear write
}

// ---------------- unified fp32 GEMM: C[n,64] = A[n,lda-K] @ B[K,64] ----------------
// r13 post-mortem: prefetch neutral — grid 391x2 caps waves at 3.05/SIMD and
// measured occupancy 20% (1.6/SIMD): one wave's prefetch slack can't cover
// L3/HBM latency. Fix: 64-row tiles — grid doubles (1564 blocks layer-1 =
// 6.1 waves/SIMD). Micro-tile 4 rows x 4 cols; A global-broadcast (16 lanes
// share ty -> 1 transaction), B in LDS, prefetch rotation retained.
// Anti-spill (r5/6/10): unroll 1 kg loop, named float4s, runtime ktn.
__global__ __launch_bounds__(256) void k_gemmN(const float* __restrict__ A,
                                               const float* __restrict__ B,
                                               float* __restrict__ C, int n,
                                               int lda, int ktn) {
    __shared__ float Bs[64][64];
    const int tid = threadIdx.x;
    const int row0 = blockIdx.x * 64;
    const int kbase = blockIdx.y * ktn * 64;
    const size_t coff = (size_t)blockIdx.y * N_NODES * HDIM;
    const int tx = tid & 15;
    const int ty = tid >> 4;
    const int tr = ty * 4;           // 4 rows per thread
    const int tc = tx * 4;           // 4 cols per thread
    const int lr = tid >> 4;         // B staging row
    const int lk = (tid & 15) * 4;   // B staging col

    const float* ar0 = A + (size_t)min(row0 + tr + 0, n - 1) * lda;
    const float* ar1 = A + (size_t)min(row0 + tr + 1, n - 1) * lda;
    const float* ar2 = A + (size_t)min(row0 + tr + 2, n - 1) * lda;
    const float* ar3 = A + (size_t)min(row0 + tr + 3, n - 1) * lda;

    float acc[4][4];
#pragma unroll
    for (int i = 0; i < 4; ++i)
#pragma unroll
        for (int j = 0; j < 4; ++j) acc[i][j] = 0.0f;

    // prime the pipeline with the first k-group
    float4 c0 = *(const float4*)(ar0 + kbase);
    float4 c1 = *(const float4*)(ar1 + kbase);
    float4 c2 = *(const float4*)(ar2 + kbase);
    float4 c3 = *(const float4*)(ar3 + kbase);

    for (int kt = 0; kt < ktn; ++kt) {
        const int kc = kbase + kt * 64;
#pragma unroll
        for (int p = 0; p < 4; ++p) {
            int kk = lr + p * 16;
            *(float4*)&Bs[kk][lk] = *(const float4*)(B + (size_t)(kc + kk) * HDIM + lk);
        }
        __syncthreads();
#pragma unroll 1
        for (int kg = 0; kg < 16; ++kg) {
            // prefetch next k-group (wraps to an in-bounds dummy at the end)
            const int k4n = (kg < 15) ? (kc + kg * 4 + 4)
                                      : ((kt < ktn - 1) ? (kc + 64) : kc);
            float4 n0 = *(const float4*)(ar0 + k4n);
            float4 n1 = *(const float4*)(ar1 + k4n);
            float4 n2 = *(const float4*)(ar2 + k4n);
            float4 n3 = *(const float4*)(ar3 + k4n);
            float4 b0 = *(const float4*)&Bs[kg * 4 + 0][tc];
            float4 b1 = *(const float4*)&Bs[kg * 4 + 1][tc];
            float4 b2 = *(const float4*)&Bs[kg * 4 + 2][tc];
            float4 b3 = *(const float4*)&Bs[kg * 4 + 3][tc];
#define ROWFMA(av, r)                                          \
            acc[r][0] = fmaf(av.x, b0.x, acc[r][0]);           \
            acc[r][1] = fmaf(av.x, b0.y, acc[r][1]);           \
            acc[r][2] = fmaf(av.x, b0.z, acc[r][2]);           \
            acc[r][3] = fmaf(av.x, b0.w, acc[r][3]);           \
            acc[r][0] = fmaf(av.y, b1.x, acc[r][0]);           \
            acc[r][1] = fmaf(av.y, b1.y, acc[r][1]);           \
            acc[r][2] = fmaf(av.y, b1.z, acc[r][2]);           \
            acc[r][3] = fmaf(av.y, b1.w, acc[r][3]);           \
            acc[r][0] = fmaf(av.z, b2.x, acc[r][0]);           \
            acc[r][1] = fmaf(av.z, b2.y, acc[r][1]);           \
            acc[r][2] = fmaf(av.z, b2.z, acc[r][2]);           \
            acc[r][3] = fmaf(av.z, b2.w, acc[r][3]);           \
            acc[r][0] = fmaf(av.w, b3.x, acc[r][0]);           \
            acc[r][1] = fmaf(av.w, b3.y, acc[r][1]);           \
            acc[r][2] = fmaf(av.w, b3.z, acc[r][2]);           \
            acc[r][3] = fmaf(av.w, b3.w, acc[r][3]);
            ROWFMA(c0, 0)
            ROWFMA(c1, 1)
            ROWFMA(c2, 2)
            ROWFMA(c3, 3)
#undef ROWFMA
            c0 = n0; c1 = n1; c2 = n2; c3 = n3;
        }
        __syncthreads();
    }
#pragma unroll
    for (int i = 0; i < 4; ++i) {
        int grow = row0 + tr + i;
        if (grow < n) {
            *(float4*)(C + coff + (size_t)grow * HDIM + tc) =
                make_float4(acc[i][0], acc[i][1], acc[i][2], acc[i][3]);
        }
    }
}

// ---------------- split-K reduction: a += b (float4) ----------------
__global__ __launch_bounds__(256) void k_sum(float4* __restrict__ a,
                                             const float4* __restrict__ b, int n4) {
    int i = blockIdx.x * 256 + threadIdx.x;
    if (i < n4) {
        float4 x = a[i], y = b[i];
        a[i] = make_float4(x.x + y.x, x.y + y.y, x.z + y.z, x.w + y.w);
    }
}

// ---------------- pull aggregation + self-loop + bias + relu ----------------
__global__ __launch_bounds__(256) void k_gather(const float* __restrict__ h,
                                                const int* __restrict__ off,
                                                const int* __restrict__ degi,
                                                const int* __restrict__ eadj,
                                                const float* __restrict__ dis,
                                                const float* __restrict__ bias,
                                                float* __restrict__ out, int n) {
    int t = blockIdx.x * 256 + threadIdx.x;
    int i = t >> 4;
    if (i >= n) return;
    int q = (t & 15) * 4;
    float di = dis[i];
    int e0 = off[i];
    int e1 = e0 + degi[i];
    float ax = 0.f, ay = 0.f, az = 0.f, aw = 0.f;
    float bx = 0.f, by = 0.f, bz = 0.f, bw = 0.f;
    int e = e0;
    for (; e + 1 < e1; e += 2) {       // unroll x2: two row loads in flight
        int s0 = eadj[e];
        int s1 = eadj[e + 1];
        float4 v0 = *(const float4*)(h + (size_t)s0 * HDIM + q);
        float4 v1 = *(const float4*)(h + (size_t)s1 * HDIM + q);
        float w0 = dis[s0] * di;
        float w1 = dis[s1] * di;
        ax = fmaf(v0.x, w0, ax); ay = fmaf(v0.y, w0, ay);
        az = fmaf(v0.z, w0, az); aw = fmaf(v0.w, w0, aw);
        bx = fmaf(v1.x, w1, bx); by = fmaf(v1.y, w1, by);
        bz = fmaf(v1.z, w1, bz); bw = fmaf(v1.w, w1, bw);
    }
    if (e < e1) {
        int s0 = eadj[e];
        float4 v0 = *(const float4*)(h + (size_t)s0 * HDIM + q);
        float w0 = dis[s0] * di;
        ax = fmaf(v0.x, w0, ax); ay = fmaf(v0.y, w0, ay);
        az = fmaf(v0.z, w0, az); aw = fmaf(v0.w, w0, aw);
    }
    ax += bx; ay += by; az += bz; aw += bw;
    float sn = di * di;                // self-loop weight = 1/(deg+1)
    float4 hv = *(const float4*)(h + (size_t)i * HDIM + q);
    float4 b = *(const float4*)(bias + q);
    ax = fmaf(hv.x, sn, ax) + b.x;
    ay = fmaf(hv.y, sn, ay) + b.y;
    az = fmaf(hv.z, sn, az) + b.z;
    aw = fmaf(hv.w, sn, aw) + b.w;
    *(float4*)(out + (size_t)i * HDIM + q) =
        make_float4(fmaxf(ax, 0.f), fmaxf(ay, 0.f), fmaxf(az, 0.f), fmaxf(aw, 0.f));
}

// ---------------- pool phase 1: partial sums, 8 segments per graph ----------------
__global__ __launch_bounds__(256) void k_pool_acc(const float* __restrict__ h,
                                                  const int* __restrict__ batch,
                                                  float* __restrict__ pooled, int n) {
    __shared__ float part[4][64];
    int g = blockIdx.x >> 3;
    int seg = blockIdx.x & 7;
    int t = threadIdx.x;
    int f = t & 63;
    int rg = t >> 6;
    int lo = 0, hi = n;
    while (lo < hi) { int m = (lo + hi) >> 1; if (batch[m] < g) lo = m + 1; else hi = m; }
    int s = lo;
    lo = 0; hi = n;
    while (lo < hi) { int m = (lo + hi) >> 1; if (batch[m] < g + 1) lo = m + 1; else hi = m; }
    int e2 = lo;
    int len = e2 - s;
    int chunk = (len + 7) >> 3;
    int i0 = s + seg * chunk;
    int i1 = min(i0 + chunk, e2);

    float sum = 0.f;
    for (int i = i0 + rg; i < i1; i += 4) sum += h[(size_t)i * HDIM + f];
    part[rg][f] = sum;
    __syncthreads();
    if (t < 64) {
        float tot = part[0][t] + part[1][t] + part[2][t] + part[3][t];
        if (tot != 0.f) atomicAdd(&pooled[g * HDIM + t], tot);
    }
}

// ---------------- pool phase 2: mean + linear head ----------------
__global__ __launch_bounds__(640) void k_head(const float* __restrict__ pooled,
                                              const int* __restrict__ batch,
                                              const float* __restrict__ linW,
                                              const float* __restrict__ linb,
                                              float* __restrict__ out, int n) {
    int t = threadIdx.x;
    if (t >= NGRAPH * NCLS) return;
    int g = t / NCLS;
    int c = t - g * NCLS;
    int lo = 0, hi = n;
    while (lo < hi) { int m = (lo + hi) >> 1; if (batch[m] < g) lo = m + 1; else hi = m; }
    int s = lo;
    lo = 0; hi = n;
    while (lo < hi) { int m = (lo + hi) >> 1; if (batch[m] < g + 1) lo = m + 1; else hi = m; }
    float inv = 1.0f / fmaxf((float)(lo - s), 1.0f);
    float acc = linb[c];
#pragma unroll
    for (int k = 0; k < HDIM; ++k)
        acc = fmaf(pooled[g * HDIM + k] * inv, linW[k * NCLS + c], acc);
    out[g * NCLS + c] = acc;
}

extern "C" void kernel_launch(void* const* d_in, const int* in_sizes, int n_in,
                              void* d_out, int out_size, void* d_ws, size_t ws_size,
                              hipStream_t stream) {
    (void)in_sizes; (void)n_in; (void)out_size; (void)ws_size;
    const float* x    = (const float*)d_in[0];
    const int*   ei   = (const int*)d_in[1];
    const int*   batch= (const int*)d_in[2];
    const float* W1   = (const float*)d_in[3];
    const float* b1   = (const float*)d_in[4];
    const float* W2   = (const float*)d_in[5];
    const float* b2   = (const float*)d_in[6];
    const float* W3   = (const float*)d_in[7];
    const float* b3   = (const float*)d_in[8];
    const float* linW = (const float*)d_in[9];
    const float* linb = (const float*)d_in[10];
    float* out = (float*)d_out;

    const int N = N_NODES, E = N_EDGES;
    const int* src = ei;
    const int* dst = ei + E;

    char* ws = (char*)d_ws;
    float* hA     = (float*)ws; ws += (size_t)N * HDIM * 4;
    float* hB     = (float*)ws; ws += (size_t)N * HDIM * 4;   // contiguous after hA (split-K)
    float* dis    = (float*)ws; ws += (size_t)N * 4;
    int*   eadj   = (int*)ws;   ws += (size_t)NBUCK * SCAP * 4;
    int*   stage  = (int*)ws;   ws += (size_t)NBUCK * SCAP * 4;
    int*   degi   = (int*)ws;   ws += (size_t)N * 4;
    int*   off    = (int*)ws;   ws += (size_t)N * 4;
    int*   bcnt   = (int*)ws;   ws += (size_t)NBUCK * 4;
    float* pooled = (float*)ws; ws += (size_t)NGRAPH * HDIM * 4;

    const int nbE = (E + 4095) / 4096;  // 196
    const int gb  = (N + 63) / 64;      // 782 (64-row tiles)
    const int ngth = (N * 16 + 255) / 256;

    hipMemsetAsync(bcnt, 0, (size_t)NBUCK * 4, stream);
    hipMemsetAsync(pooled, 0, (size_t)NGRAPH * HDIM * 4, stream);
    k_part<<<nbE, 256, 0, stream>>>(src, dst, bcnt, stage, E);
    k_csr<<<NBUCK, 256, 0, stream>>>(stage, bcnt, degi, dis, off, eadj, N);

    // layer 1: split-K x2 (y=0 -> hA, y=1 -> hB), then hA += hB
    k_gemmN<<<dim3(gb, 2), 256, 0, stream>>>(x, W1, hA, N, F_INPUT, 2);
    k_sum<<<(N * HDIM / 4 + 255) / 256, 256, 0, stream>>>((float4*)hA, (const float4*)hB,
                                                          N * HDIM / 4);
    k_gather<<<ngth, 256, 0, stream>>>(hA, off, degi, eadj, dis, b1, hB, N);
    // layer 2
    k_gemmN<<<dim3(gb, 1), 256, 0, stream>>>(hB, W2, hA, N, HDIM, 1);
    k_gather<<<ngth, 256, 0, stream>>>(hA, off, degi, eadj, dis, b2, hB, N);
    // layer 3
    k_gemmN<<<dim3(gb, 1), 256, 0, stream>>>(hB, W3, hA, N, HDIM, 1);
    k_gather<<<ngth, 256, 0, stream>>>(hA, off, degi, eadj, dis, b3, hB, N);
    // pool + head
    k_pool_acc<<<NGRAPH * 8, 256, 0, stream>>>(hB, batch, pooled, N);
    k_head<<<1, 640, 0, stream>>>(pooled, batch, linW, linb, out, N);
}

// Round 15
// 277.981 us; speedup vs baseline: 1.1772x; 1.1772x over previous
//
#include <hip/hip_runtime.h>

#define N_NODES 50000
#define N_EDGES 800000
#define F_INPUT 256
#define HDIM 64
#define NCLS 10
#define NGRAPH 64

#define BSHIFT 7                 // 128 nodes per bucket
#define NBUCK 391                // ceil(50000/128)
#define SCAP 4096                // per-bucket stage/eadj capacity (mean 2046, 45 sigma)

// bf16 helpers: storage-only precision cut; all arithmetic stays fp32.
__device__ __forceinline__ float bflo(unsigned v) { return __uint_as_float(v << 16); }
__device__ __forceinline__ float bfhi(unsigned v) { return __uint_as_float(v & 0xFFFF0000u); }
__device__ __forceinline__ unsigned f2b2(float a, float b) {   // pack 2 floats -> 2 bf16 (RNE)
    unsigned x = __float_as_uint(a); x = (x + 0x7FFF + ((x >> 16) & 1)) >> 16;
    unsigned y = __float_as_uint(b); y = (y + 0x7FFF + ((y >> 16) & 1)) >> 16;
    return x | (y << 16);
}

// ---------------- pass A: LDS-staged bucket partition ----------------
__global__ __launch_bounds__(256) void k_part(const int* __restrict__ src,
                                              const int* __restrict__ dst,
                                              int* __restrict__ bcnt,
                                              int* __restrict__ stage, int E) {
    __shared__ int cnt[NBUCK];
    __shared__ int base[NBUCK];
    const int tid = threadIdx.x;
    const int e0 = blockIdx.x * 4096;
    int pb[16], pv[16];
    for (int t = tid; t < NBUCK; t += 256) cnt[t] = 0;
    __syncthreads();
#pragma unroll
    for (int j = 0; j < 16; ++j) {
        int e = e0 + j * 256 + tid;
        if (e < E) {
            int s = src[e], d = dst[e];
            pb[j] = d >> BSHIFT;
            pv[j] = (s << BSHIFT) | (d & 127);
            atomicAdd(&cnt[pb[j]], 1);
        } else pb[j] = -1;
    }
    __syncthreads();
    for (int t = tid; t < NBUCK; t += 256) {
        int c = cnt[t];
        base[t] = c ? atomicAdd(&bcnt[t], c) : 0;
        cnt[t] = 0;
    }
    __syncthreads();
#pragma unroll
    for (int j = 0; j < 16; ++j) {
        if (pb[j] >= 0) {
            int r = base[pb[j]] + atomicAdd(&cnt[pb[j]], 1);
            if (r < SCAP) stage[pb[j] * SCAP + r] = pv[j];  // 45-sigma clamp
        }
    }
}

// ---------------- pass B: per-bucket degree + scan + counting sort ----------------
__global__ __launch_bounds__(256) void k_csr(const int* __restrict__ stage,
                                             const int* __restrict__ bcnt,
                                             int* __restrict__ degi,
                                             float* __restrict__ dis,
                                             int* __restrict__ off,
                                             int* __restrict__ eadj, int n) {
    __shared__ int cnt[128];
    __shared__ int loc[128];
    __shared__ int lcur[128];
    __shared__ int ebuf[SCAP];   // 16 KB
    const int b = blockIdx.x;
    const int tid = threadIdx.x;
    const int n0 = b << BSHIFT;
    const int nn = min(128, n - n0);
    const int sb = b * SCAP;
    const int len = min(bcnt[b], SCAP);
    if (tid < 128) cnt[tid] = 0;
    __syncthreads();
    for (int j = tid; j < len; j += 256) atomicAdd(&cnt[stage[sb + j] & 127], 1);
    __syncthreads();
    if (tid < nn) {
        int dg = cnt[tid];
        degi[n0 + tid] = dg;
        dis[n0 + tid] = rsqrtf((float)(dg + 1));
    }
    if (tid < 128) loc[tid] = cnt[tid];
    __syncthreads();
    for (int d = 1; d < 128; d <<= 1) {       // Hillis-Steele inclusive scan
        int x = 0;
        if (tid < 128 && tid >= d) x = loc[tid - d];
        __syncthreads();
        if (tid < 128) loc[tid] += x;
        __syncthreads();
    }
    if (tid < 128) {
        int ex = loc[tid] - cnt[tid];          // exclusive
        if (tid < nn) off[n0 + tid] = sb + ex;
        lcur[tid] = ex;
    }
    __syncthreads();
    for (int j = tid; j < len; j += 256) {
        int p = stage[sb + j];
        int rk = atomicAdd(&lcur[p & 127], 1);
        ebuf[rk] = p >> BSHIFT;
    }
    __syncthreads();
    for (int j = tid; j < len; j += 256) eadj[sb + j] = ebuf[j];  // linear write
}

// ---------------- GEMM (fp32 A): Cbf16[n,64] = A[n,lda] @ B[lda-K,64] ----------------
// r14 structure (A global-broadcast, B LDS, prefetch rotation, 64-row tile,
// anti-spill: unroll-1 kg, named float4s, runtime ktn). Output packed bf16.
__global__ __launch_bounds__(256) void k_gemmF(const float* __restrict__ A,
                                               const float* __restrict__ B,
                                               unsigned short* __restrict__ C, int n,
                                               int lda, int ktn) {
    __shared__ float Bs[64][64];
    const int tid = threadIdx.x;
    const int row0 = blockIdx.x * 64;
    const int tx = tid & 15;
    const int ty = tid >> 4;
    const int tr = ty * 4;
    const int tc = tx * 4;
    const int lr = tid >> 4;
    const int lk = (tid & 15) * 4;

    const float* ar0 = A + (size_t)min(row0 + tr + 0, n - 1) * lda;
    const float* ar1 = A + (size_t)min(row0 + tr + 1, n - 1) * lda;
    const float* ar2 = A + (size_t)min(row0 + tr + 2, n - 1) * lda;
    const float* ar3 = A + (size_t)min(row0 + tr + 3, n - 1) * lda;

    float acc[4][4];
#pragma unroll
    for (int i = 0; i < 4; ++i)
#pragma unroll
        for (int j = 0; j < 4; ++j) acc[i][j] = 0.0f;

    float4 c0 = *(const float4*)(ar0);
    float4 c1 = *(const float4*)(ar1);
    float4 c2 = *(const float4*)(ar2);
    float4 c3 = *(const float4*)(ar3);

    for (int kt = 0; kt < ktn; ++kt) {
        const int kc = kt * 64;
#pragma unroll
        for (int p = 0; p < 4; ++p) {
            int kk = lr + p * 16;
            *(float4*)&Bs[kk][lk] = *(const float4*)(B + (size_t)(kc + kk) * HDIM + lk);
        }
        __syncthreads();
#pragma unroll 1
        for (int kg = 0; kg < 16; ++kg) {
            const int k4n = (kg < 15) ? (kc + kg * 4 + 4)
                                      : ((kt < ktn - 1) ? (kc + 64) : kc);
            float4 n0 = *(const float4*)(ar0 + k4n);
            float4 n1 = *(const float4*)(ar1 + k4n);
            float4 n2 = *(const float4*)(ar2 + k4n);
            float4 n3 = *(const float4*)(ar3 + k4n);
            float4 b0 = *(const float4*)&Bs[kg * 4 + 0][tc];
            float4 b1 = *(const float4*)&Bs[kg * 4 + 1][tc];
            float4 b2 = *(const float4*)&Bs[kg * 4 + 2][tc];
            float4 b3 = *(const float4*)&Bs[kg * 4 + 3][tc];
#define ROWFMA(av, r)                                          \
            acc[r][0] = fmaf(av.x, b0.x, acc[r][0]);           \
            acc[r][1] = fmaf(av.x, b0.y, acc[r][1]);           \
            acc[r][2] = fmaf(av.x, b0.z, acc[r][2]);           \
            acc[r][3] = fmaf(av.x, b0.w, acc[r][3]);           \
            acc[r][0] = fmaf(av.y, b1.x, acc[r][0]);           \
            acc[r][1] = fmaf(av.y, b1.y, acc[r][1]);           \
            acc[r][2] = fmaf(av.y, b1.z, acc[r][2]);           \
            acc[r][3] = fmaf(av.y, b1.w, acc[r][3]);           \
            acc[r][0] = fmaf(av.z, b2.x, acc[r][0]);           \
            acc[r][1] = fmaf(av.z, b2.y, acc[r][1]);           \
            acc[r][2] = fmaf(av.z, b2.z, acc[r][2]);           \
            acc[r][3] = fmaf(av.z, b2.w, acc[r][3]);           \
            acc[r][0] = fmaf(av.w, b3.x, acc[r][0]);           \
            acc[r][1] = fmaf(av.w, b3.y, acc[r][1]);           \
            acc[r][2] = fmaf(av.w, b3.z, acc[r][2]);           \
            acc[r][3] = fmaf(av.w, b3.w, acc[r][3]);
            ROWFMA(c0, 0)
            ROWFMA(c1, 1)
            ROWFMA(c2, 2)
            ROWFMA(c3, 3)
            c0 = n0; c1 = n1; c2 = n2; c3 = n3;
        }
        __syncthreads();
    }
#pragma unroll
    for (int i = 0; i < 4; ++i) {
        int grow = row0 + tr + i;
        if (grow < n) {
            uint2 p;
            p.x = f2b2(acc[i][0], acc[i][1]);
            p.y = f2b2(acc[i][2], acc[i][3]);
            *(uint2*)(C + (size_t)grow * HDIM + tc) = p;
        }
    }
}

// ---------------- GEMM (bf16 A): same structure, A rows are packed bf16 ----------------
__global__ __launch_bounds__(256) void k_gemmB(const unsigned short* __restrict__ A,
                                               const float* __restrict__ B,
                                               unsigned short* __restrict__ C, int n,
                                               int lda, int ktn) {
    __shared__ float Bs[64][64];
    const int tid = threadIdx.x;
    const int row0 = blockIdx.x * 64;
    const int tx = tid & 15;
    const int ty = tid >> 4;
    const int tr = ty * 4;
    const int tc = tx * 4;
    const int lr = tid >> 4;
    const int lk = (tid & 15) * 4;

    const unsigned short* ar0 = A + (size_t)min(row0 + tr + 0, n - 1) * lda;
    const unsigned short* ar1 = A + (size_t)min(row0 + tr + 1, n - 1) * lda;
    const unsigned short* ar2 = A + (size_t)min(row0 + tr + 2, n - 1) * lda;
    const unsigned short* ar3 = A + (size_t)min(row0 + tr + 3, n - 1) * lda;

    float acc[4][4];
#pragma unroll
    for (int i = 0; i < 4; ++i)
#pragma unroll
        for (int j = 0; j < 4; ++j) acc[i][j] = 0.0f;

    uint2 c0 = *(const uint2*)(ar0);   // 4 bf16
    uint2 c1 = *(const uint2*)(ar1);
    uint2 c2 = *(const uint2*)(ar2);
    uint2 c3 = *(const uint2*)(ar3);

    for (int kt = 0; kt < ktn; ++kt) {
        const int kc = kt * 64;
#pragma unroll
        for (int p = 0; p < 4; ++p) {
            int kk = lr + p * 16;
            *(float4*)&Bs[kk][lk] = *(const float4*)(B + (size_t)(kc + kk) * HDIM + lk);
        }
        __syncthreads();
#pragma unroll 1
        for (int kg = 0; kg < 16; ++kg) {
            const int k4n = (kg < 15) ? (kc + kg * 4 + 4)
                                      : ((kt < ktn - 1) ? (kc + 64) : kc);
            uint2 n0 = *(const uint2*)(ar0 + k4n);
            uint2 n1 = *(const uint2*)(ar1 + k4n);
            uint2 n2 = *(const uint2*)(ar2 + k4n);
            uint2 n3 = *(const uint2*)(ar3 + k4n);
            float4 b0 = *(const float4*)&Bs[kg * 4 + 0][tc];
            float4 b1 = *(const float4*)&Bs[kg * 4 + 1][tc];
            float4 b2 = *(const float4*)&Bs[kg * 4 + 2][tc];
            float4 b3 = *(const float4*)&Bs[kg * 4 + 3][tc];
#define ROWFMB(u, r)                                                        \
            { float x0 = bflo(u.x), x1 = bfhi(u.x), x2 = bflo(u.y), x3 = bfhi(u.y); \
            acc[r][0] = fmaf(x0, b0.x, acc[r][0]);                          \
            acc[r][1] = fmaf(x0, b0.y, acc[r][1]);                          \
            acc[r][2] = fmaf(x0, b0.z, acc[r][2]);                          \
            acc[r][3] = fmaf(x0, b0.w, acc[r][3]);                          \
            acc[r][0] = fmaf(x1, b1.x, acc[r][0]);                          \
            acc[r][1] = fmaf(x1, b1.y, acc[r][1]);                          \
            acc[r][2] = fmaf(x1, b1.z, acc[r][2]);                          \
            acc[r][3] = fmaf(x1, b1.w, acc[r][3]);                          \
            acc[r][0] = fmaf(x2, b2.x, acc[r][0]);                          \
            acc[r][1] = fmaf(x2, b2.y, acc[r][1]);                          \
            acc[r][2] = fmaf(x2, b2.z, acc[r][2]);                          \
            acc[r][3] = fmaf(x2, b2.w, acc[r][3]);                          \
            acc[r][0] = fmaf(x3, b3.x, acc[r][0]);                          \
            acc[r][1] = fmaf(x3, b3.y, acc[r][1]);                          \
            acc[r][2] = fmaf(x3, b3.z, acc[r][2]);                          \
            acc[r][3] = fmaf(x3, b3.w, acc[r][3]); }
            ROWFMB(c0, 0)
            ROWFMB(c1, 1)
            ROWFMB(c2, 2)
            ROWFMB(c3, 3)
#undef ROWFMB
            c0 = n0; c1 = n1; c2 = n2; c3 = n3;
        }
        __syncthreads();
    }
#pragma unroll
    for (int i = 0; i < 4; ++i) {
        int grow = row0 + tr + i;
        if (grow < n) {
            uint2 p;
            p.x = f2b2(acc[i][0], acc[i][1]);
            p.y = f2b2(acc[i][2], acc[i][3]);
            *(uint2*)(C + (size_t)grow * HDIM + tc) = p;
        }
    }
}

// ---------------- pull aggregation (bf16 rows) + self + bias + relu -> bf16 ----------------
// 8 lanes/node, each owns 8 features (one uint4 = 8 bf16). Row read per edge:
// 128 B (was 256 B fp32) — halves the L2/L3 gather traffic that dominates.
__global__ __launch_bounds__(256) void k_gather_b(const unsigned short* __restrict__ h,
                                                  const int* __restrict__ off,
                                                  const int* __restrict__ degi,
                                                  const int* __restrict__ eadj,
                                                  const float* __restrict__ dis,
                                                  const float* __restrict__ bias,
                                                  unsigned short* __restrict__ out, int n) {
    int t = blockIdx.x * 256 + threadIdx.x;
    int i = t >> 3;
    if (i >= n) return;
    int q = (t & 7) * 8;
    float di = dis[i];
    int e0 = off[i];
    int e1 = e0 + degi[i];
    float a0 = 0.f, a1 = 0.f, a2 = 0.f, a3 = 0.f, a4 = 0.f, a5 = 0.f, a6 = 0.f, a7 = 0.f;
    float g0 = 0.f, g1 = 0.f, g2 = 0.f, g3 = 0.f, g4 = 0.f, g5 = 0.f, g6 = 0.f, g7 = 0.f;
    int e = e0;
    for (; e + 1 < e1; e += 2) {
        int s0 = eadj[e];
        int s1 = eadj[e + 1];
        uint4 u0 = *(const uint4*)(h + (size_t)s0 * HDIM + q);
        uint4 u1 = *(const uint4*)(h + (size_t)s1 * HDIM + q);
        float w0 = dis[s0] * di;
        float w1 = dis[s1] * di;
        a0 = fmaf(bflo(u0.x), w0, a0); a1 = fmaf(bfhi(u0.x), w0, a1);
        a2 = fmaf(bflo(u0.y), w0, a2); a3 = fmaf(bfhi(u0.y), w0, a3);
        a4 = fmaf(bflo(u0.z), w0, a4); a5 = fmaf(bfhi(u0.z), w0, a5);
        a6 = fmaf(bflo(u0.w), w0, a6); a7 = fmaf(bfhi(u0.w), w0, a7);
        g0 = fmaf(bflo(u1.x), w1, g0); g1 = fmaf(bfhi(u1.x), w1, g1);
        g2 = fmaf(bflo(u1.y), w1, g2); g3 = fmaf(bfhi(u1.y), w1, g3);
        g4 = fmaf(bflo(u1.z), w1, g4); g5 = fmaf(bfhi(u1.z), w1, g5);
        g6 = fmaf(bflo(u1.w), w1, g6); g7 = fmaf(bfhi(u1.w), w1, g7);
    }
    if (e < e1) {
        int s0 = eadj[e];
        uint4 u0 = *(const uint4*)(h + (size_t)s0 * HDIM + q);
        float w0 = dis[s0] * di;
        a0 = fmaf(bflo(u0.x), w0, a0); a1 = fmaf(bfhi(u0.x), w0, a1);
        a2 = fmaf(bflo(u0.y), w0, a2); a3 = fmaf(bfhi(u0.y), w0, a3);
        a4 = fmaf(bflo(u0.z), w0, a4); a5 = fmaf(bfhi(u0.z), w0, a5);
        a6 = fmaf(bflo(u0.w), w0, a6); a7 = fmaf(bfhi(u0.w), w0, a7);
    }
    a0 += g0; a1 += g1; a2 += g2; a3 += g3;
    a4 += g4; a5 += g5; a6 += g6; a7 += g7;
    float sn = di * di;
    uint4 us = *(const uint4*)(h + (size_t)i * HDIM + q);
    float4 bl = *(const float4*)(bias + q);
    float4 bh = *(const float4*)(bias + q + 4);
    a0 = fmaxf(fmaf(bflo(us.x), sn, a0) + bl.x, 0.f);
    a1 = fmaxf(fmaf(bfhi(us.x), sn, a1) + bl.y, 0.f);
    a2 = fmaxf(fmaf(bflo(us.y), sn, a2) + bl.z, 0.f);
    a3 = fmaxf(fmaf(bfhi(us.y), sn, a3) + bl.w, 0.f);
    a4 = fmaxf(fmaf(bflo(us.z), sn, a4) + bh.x, 0.f);
    a5 = fmaxf(fmaf(bfhi(us.z), sn, a5) + bh.y, 0.f);
    a6 = fmaxf(fmaf(bflo(us.w), sn, a6) + bh.z, 0.f);
    a7 = fmaxf(fmaf(bfhi(us.w), sn, a7) + bh.w, 0.f);
    uint4 o;
    o.x = f2b2(a0, a1); o.y = f2b2(a2, a3);
    o.z = f2b2(a4, a5); o.w = f2b2(a6, a7);
    *(uint4*)(out + (size_t)i * HDIM + q) = o;
}

// ---------------- layer-3 gather fused with mean-pool accumulate ----------------
// Same aggregation; instead of writing h3, accumulates fp32 into per-block LDS
// graph table then flushes the (sorted-batch) touched graph rows with global
// atomics (~1-2 rows/block).
__global__ __launch_bounds__(256) void k_gather_pool(const unsigned short* __restrict__ h,
                                                     const int* __restrict__ off,
                                                     const int* __restrict__ degi,
                                                     const int* __restrict__ eadj,
                                                     const float* __restrict__ dis,
                                                     const float* __restrict__ bias,
                                                     const int* __restrict__ batch,
                                                     float* __restrict__ pooled, int n) {
    __shared__ float sp[NGRAPH][HDIM];   // 16 KB
    const int tid = threadIdx.x;
    int t = blockIdx.x * 256 + tid;
    int i = t >> 3;
    const bool valid = (i < n);
    int q = (t & 7) * 8;
    const int i0 = (blockIdx.x * 256) >> 3;
    const int i1 = min(i0 + 32, n);
    const int gmin = batch[min(i0, n - 1)];
    const int gmax = batch[i1 - 1];
    for (int j = tid; j < NGRAPH * HDIM; j += 256) ((float*)sp)[j] = 0.f;
    __syncthreads();
    if (valid) {
        float di = dis[i];
        int e0 = off[i];
        int e1 = e0 + degi[i];
        float a0 = 0.f, a1 = 0.f, a2 = 0.f, a3 = 0.f, a4 = 0.f, a5 = 0.f, a6 = 0.f, a7 = 0.f;
        float g0 = 0.f, g1 = 0.f, g2 = 0.f, g3 = 0.f, g4 = 0.f, g5 = 0.f, g6 = 0.f, g7 = 0.f;
        int e = e0;
        for (; e + 1 < e1; e += 2) {
            int s0 = eadj[e];
            int s1 = eadj[e + 1];
            uint4 u0 = *(const uint4*)(h + (size_t)s0 * HDIM + q);
            uint4 u1 = *(const uint4*)(h + (size_t)s1 * HDIM + q);
            float w0 = dis[s0] * di;
            float w1 = dis[s1] * di;
            a0 = fmaf(bflo(u0.x), w0, a0); a1 = fmaf(bfhi(u0.x), w0, a1);
            a2 = fmaf(bflo(u0.y), w0, a2); a3 = fmaf(bfhi(u0.y), w0, a3);
            a4 = fmaf(bflo(u0.z), w0, a4); a5 = fmaf(bfhi(u0.z), w0, a5);
            a6 = fmaf(bflo(u0.w), w0, a6); a7 = fmaf(bfhi(u0.w), w0, a7);
            g0 = fmaf(bflo(u1.x), w1, g0); g1 = fmaf(bfhi(u1.x), w1, g1);
            g2 = fmaf(bflo(u1.y), w1, g2); g3 = fmaf(bfhi(u1.y), w1, g3);
            g4 = fmaf(bflo(u1.z), w1, g4); g5 = fmaf(bfhi(u1.z), w1, g5);
            g6 = fmaf(bflo(u1.w), w1, g6); g7 = fmaf(bfhi(u1.w), w1, g7);
        }
        if (e < e1) {
            int s0 = eadj[e];
            uint4 u0 = *(const uint4*)(h + (size_t)s0 * HDIM + q);
            float w0 = dis[s0] * di;
            a0 = fmaf(bflo(u0.x), w0, a0); a1 = fmaf(bfhi(u0.x), w0, a1);
            a2 = fmaf(bflo(u0.y), w0, a2); a3 = fmaf(bfhi(u0.y), w0, a3);
            a4 = fmaf(bflo(u0.z), w0, a4); a5 = fmaf(bfhi(u0.z), w0, a5);
            a6 = fmaf(bflo(u0.w), w0, a6); a7 = fmaf(bfhi(u0.w), w0, a7);
        }
        a0 += g0; a1 += g1; a2 += g2; a3 += g3;
        a4 += g4; a5 += g5; a6 += g6; a7 += g7;
        float sn = di * di;
        uint4 us = *(const uint4*)(h + (size_t)i * HDIM + q);
        float4 bl = *(const float4*)(bias + q);
        float4 bh = *(const float4*)(bias + q + 4);
        a0 = fmaxf(fmaf(bflo(us.x), sn, a0) + bl.x, 0.f);
        a1 = fmaxf(fmaf(bfhi(us.x), sn, a1) + bl.y, 0.f);
        a2 = fmaxf(fmaf(bflo(us.y), sn, a2) + bl.z, 0.f);
        a3 = fmaxf(fmaf(bfhi(us.y), sn, a3) + bl.w, 0.f);
        a4 = fmaxf(fmaf(bflo(us.z), sn, a4) + bh.x, 0.f);
        a5 = fmaxf(fmaf(bfhi(us.z), sn, a5) + bh.y, 0.f);
        a6 = fmaxf(fmaf(bflo(us.w), sn, a6) + bh.z, 0.f);
        a7 = fmaxf(fmaf(bfhi(us.w), sn, a7) + bh.w, 0.f);
        int g = batch[i];
        atomicAdd(&sp[g][q + 0], a0); atomicAdd(&sp[g][q + 1], a1);
        atomicAdd(&sp[g][q + 2], a2); atomicAdd(&sp[g][q + 3], a3);
        atomicAdd(&sp[g][q + 4], a4); atomicAdd(&sp[g][q + 5], a5);
        atomicAdd(&sp[g][q + 6], a6); atomicAdd(&sp[g][q + 7], a7);
    }
    __syncthreads();
    int rows = gmax - gmin + 1;
    for (int j = tid; j < rows * HDIM; j += 256) {
        int r = j >> 6, c = j & 63;
        float v = sp[gmin + r][c];
        if (v != 0.f) atomicAdd(&pooled[(gmin + r) * HDIM + c], v);
    }
}

// ---------------- mean + linear head ----------------
__global__ __launch_bounds__(640) void k_head(const float* __restrict__ pooled,
                                              const int* __restrict__ batch,
                                              const float* __restrict__ linW,
                                              const float* __restrict__ linb,
                                              float* __restrict__ out, int n) {
    int t = threadIdx.x;
    if (t >= NGRAPH * NCLS) return;
    int g = t / NCLS;
    int c = t - g * NCLS;
    int lo = 0, hi = n;
    while (lo < hi) { int m = (lo + hi) >> 1; if (batch[m] < g) lo = m + 1; else hi = m; }
    int s = lo;
    lo = 0; hi = n;
    while (lo < hi) { int m = (lo + hi) >> 1; if (batch[m] < g + 1) lo = m + 1; else hi = m; }
    float inv = 1.0f / fmaxf((float)(lo - s), 1.0f);
    float acc = linb[c];
#pragma unroll
    for (int k = 0; k < HDIM; ++k)
        acc = fmaf(pooled[g * HDIM + k] * inv, linW[k * NCLS + c], acc);
    out[g * NCLS + c] = acc;
}

extern "C" void kernel_launch(void* const* d_in, const int* in_sizes, int n_in,
                              void* d_out, int out_size, void* d_ws, size_t ws_size,
                              hipStream_t stream) {
    (void)in_sizes; (void)n_in; (void)out_size; (void)ws_size;
    const float* x    = (const float*)d_in[0];
    const int*   ei   = (const int*)d_in[1];
    const int*   batch= (const int*)d_in[2];
    const float* W1   = (const float*)d_in[3];
    const float* b1   = (const float*)d_in[4];
    const float* W2   = (const float*)d_in[5];
    const float* b2   = (const float*)d_in[6];
    const float* W3   = (const float*)d_in[7];
    const float* b3   = (const float*)d_in[8];
    const float* linW = (const float*)d_in[9];
    const float* linb = (const float*)d_in[10];
    float* out = (float*)d_out;

    const int N = N_NODES, E = N_EDGES;
    const int* src = ei;
    const int* dst = ei + E;

    char* ws = (char*)d_ws;
    unsigned short* hA = (unsigned short*)ws; ws += (size_t)N * HDIM * 2;
    unsigned short* hB = (unsigned short*)ws; ws += (size_t)N * HDIM * 2;
    float* dis    = (float*)ws; ws += (size_t)N * 4;
    int*   eadj   = (int*)ws;   ws += (size_t)NBUCK * SCAP * 4;
    int*   stage  = (int*)ws;   ws += (size_t)NBUCK * SCAP * 4;
    int*   degi   = (int*)ws;   ws += (size_t)N * 4;
    int*   off    = (int*)ws;   ws += (size_t)N * 4;
    int*   bcnt   = (int*)ws;   ws += (size_t)NBUCK * 4;
    float* pooled = (float*)ws; ws += (size_t)NGRAPH * HDIM * 4;

    const int nbE = (E + 4095) / 4096;   // 196
    const int gb  = (N + 63) / 64;       // 782
    const int ngth = (N * 8 + 255) / 256; // 1563

    hipMemsetAsync(bcnt, 0, (size_t)NBUCK * 4, stream);
    hipMemsetAsync(pooled, 0, (size_t)NGRAPH * HDIM * 4, stream);
    k_part<<<nbE, 256, 0, stream>>>(src, dst, bcnt, stage, E);
    k_csr<<<NBUCK, 256, 0, stream>>>(stage, bcnt, degi, dis, off, eadj, N);

    // layer 1 (fp32 x -> bf16 h1)
    k_gemmF<<<gb, 256, 0, stream>>>(x, W1, hA, N, F_INPUT, 4);
    k_gather_b<<<ngth, 256, 0, stream>>>(hA, off, degi, eadj, dis, b1, hB, N);
    // layer 2
    k_gemmB<<<gb, 256, 0, stream>>>(hB, W2, hA, N, HDIM, 1);
    k_gather_b<<<ngth, 256, 0, stream>>>(hA, off, degi, eadj, dis, b2, hB, N);
    // layer 3 (gather fused with pooling)
    k_gemmB<<<gb, 256, 0, stream>>>(hB, W3, hA, N, HDIM, 1);
    k_gather_pool<<<ngth, 256, 0, stream>>>(hA, off, degi, eadj, dis, b3, batch, pooled, N);
    // head
    k_head<<<1, 640, 0, stream>>>(pooled, batch, linW, linb, out, N);
}